// Round 5
// baseline (942.011 us; speedup 1.0000x reference)
//
#include <hip/hip_runtime.h>

// Problem constants (fixed by the reference)
#define N_TOKENS 32768
#define N_CODES  8192
#define DIM      512

// Tiling: 128 token-rows x 256 codes per tile, BK=32, 4 code-slices.
// Rationale (round-3 post-mortem): kernel is ds_read_b128-throughput-bound
// (~92% LDS pipe busy at 64x64 wave tiles). 64x128 wave tiles cut LDS reads
// per FLOP by 25% (reads ~ (rows+cols), FLOPs ~ rows*cols).
#define BMT 128
#define BNT 256
#define SLICES 4
#define SLICE_CODES (N_CODES / SLICES)   // 2048
#define NTILES (SLICE_CODES / BNT)       // 8
#define BK 32
#define CHUNKS (DIM / BK)                // 16

// Output layout (FP32 elements, reference return order)
#define OUT_VQ     16777216
#define OUT_COMMIT 16777217
#define OUT_IDX    16777218

// Workspace byte offsets
#define WS_CBHI 0                         //  8 MB codebook f16 hi
#define WS_CBLO 8388608                   //  8 MB codebook f16 lo
#define WS_NC   16777216                  // 32 KB code norms
#define WS_PART 16809984                  //  1 MB slice partials
#define WS_ACC  17858560                  //  4 B loss accum
#define WS_ZEHI 18874368                  // 32 MB z_e f16 hi
#define WS_ZELO 52428800                  // 32 MB z_e f16 lo
#define WS_NEED_FAST 85983232             // total for pre-split-A path

typedef _Float16 f16x8 __attribute__((ext_vector_type(8)));
typedef _Float16 f16x4 __attribute__((ext_vector_type(4)));
typedef float    f32x4 __attribute__((ext_vector_type(4)));

// Swizzled LDS half-index for (row, kgrp) in a [rows][32]-half plane (row
// stride 64B). slot = kgrp ^ ((row>>1)&3); with row parity this gives the
// free 2-lanes-per-bank minimum for wave64 b128 reads (verified rounds 2-3:
// SQ_LDS_BANK_CONFLICT unchanged vs baseline).
__device__ __forceinline__ int sw32(int row, int kgrp) {
    return row * 32 + (((kgrp ^ ((row >> 1) & 3))) << 3);
}

// async 16B global->LDS (lds dest = wave-uniform base + lane*16)
__device__ __forceinline__ void async_copy16(void* lds, const void* g) {
    __builtin_amdgcn_global_load_lds(
        (const __attribute__((address_space(1))) unsigned int*)g,
        (__attribute__((address_space(3))) unsigned int*)lds,
        16, 0, 0);
}

// ---------------------------------------------------------------------------
// Kernel 1a: codebook -> planar f16 hi/lo + squared norms + zero accum.
__global__ void vq_prep_cb_kernel(const float* __restrict__ cb,
                                  _Float16* __restrict__ cb_hi,
                                  _Float16* __restrict__ cb_lo,
                                  float* __restrict__ nc,
                                  float* __restrict__ accum) {
    if (blockIdx.x == 0 && threadIdx.x == 0) *accum = 0.0f;
    const int wid  = threadIdx.x >> 6;
    const int lane = threadIdx.x & 63;
    const int row  = blockIdx.x * 4 + wid;
    const float4* src = (const float4*)(cb + (size_t)row * DIM);
    float4 v0 = src[lane * 2];
    float4 v1 = src[lane * 2 + 1];
    float s = v0.x*v0.x + v0.y*v0.y + v0.z*v0.z + v0.w*v0.w
            + v1.x*v1.x + v1.y*v1.y + v1.z*v1.z + v1.w*v1.w;
    f16x8 hi = {(_Float16)v0.x, (_Float16)v0.y, (_Float16)v0.z, (_Float16)v0.w,
                (_Float16)v1.x, (_Float16)v1.y, (_Float16)v1.z, (_Float16)v1.w};
    f16x8 lo = {(_Float16)(v0.x - (float)hi[0]), (_Float16)(v0.y - (float)hi[1]),
                (_Float16)(v0.z - (float)hi[2]), (_Float16)(v0.w - (float)hi[3]),
                (_Float16)(v1.x - (float)hi[4]), (_Float16)(v1.y - (float)hi[5]),
                (_Float16)(v1.z - (float)hi[6]), (_Float16)(v1.w - (float)hi[7])};
    *(f16x8*)&cb_hi[(size_t)row * DIM + lane * 8] = hi;
    *(f16x8*)&cb_lo[(size_t)row * DIM + lane * 8] = lo;
#pragma unroll
    for (int off = 32; off > 0; off >>= 1) s += __shfl_down(s, off);
    if (lane == 0) nc[row] = s;
}

// Kernel 1b: z_e -> planar f16 hi/lo (fast path only).
__global__ void vq_prep_ze_kernel(const float* __restrict__ z_e,
                                  _Float16* __restrict__ ze_hi,
                                  _Float16* __restrict__ ze_lo) {
    const int wid  = threadIdx.x >> 6;
    const int lane = threadIdx.x & 63;
    const int row  = blockIdx.x * 4 + wid;
    const float4* src = (const float4*)(z_e + (size_t)row * DIM);
    float4 v0 = src[lane * 2];
    float4 v1 = src[lane * 2 + 1];
    f16x8 hi = {(_Float16)v0.x, (_Float16)v0.y, (_Float16)v0.z, (_Float16)v0.w,
                (_Float16)v1.x, (_Float16)v1.y, (_Float16)v1.z, (_Float16)v1.w};
    f16x8 lo = {(_Float16)(v0.x - (float)hi[0]), (_Float16)(v0.y - (float)hi[1]),
                (_Float16)(v0.z - (float)hi[2]), (_Float16)(v0.w - (float)hi[3]),
                (_Float16)(v1.x - (float)hi[4]), (_Float16)(v1.y - (float)hi[5]),
                (_Float16)(v1.z - (float)hi[6]), (_Float16)(v1.w - (float)hi[7])};
    *(f16x8*)&ze_hi[(size_t)row * DIM + lane * 8] = hi;
    *(f16x8*)&ze_lo[(size_t)row * DIM + lane * 8] = lo;
}

// ---------------------------------------------------------------------------
// Kernel 2: 3-plane f16-split GEMM + per-slice argmin.
// Round-0 sync structure (stage -> drain-barrier -> compute -> barrier);
// intra-block pipelining was tested (rounds 2-3) and regressed — with
// 2 blocks/CU the inter-block wave overlap already covers the drain.
// Wave tile 64x128 (2x2 waves over 128x256): 24 ds_read_b128 per wave per
// 64-k instead of 32 (-25% on the binding LDS-read pipe).
template <bool PRESPLIT>
__global__ __launch_bounds__(256, 2)
void vq_main_kernel(const float* __restrict__ z_e,
                    const _Float16* __restrict__ ze_hi,
                    const _Float16* __restrict__ ze_lo,
                    const _Float16* __restrict__ cb_hi,
                    const _Float16* __restrict__ cb_lo,
                    const float* __restrict__ nc,
                    float2* __restrict__ partials) {
    // 48 KB LDS (half-indices): As_hi 0, As_lo 4096, Bs_hi 8192, Bs_lo 16384
    //   A planes: [128][32] halves (8KB each); B planes: [256][32] (16KB each)
    __shared__ __align__(16) unsigned char smem[49152];
    _Float16* As_hi = (_Float16*)smem;
    _Float16* As_lo = (_Float16*)smem + 4096;
    _Float16* Bs_hi = (_Float16*)smem + 8192;
    _Float16* Bs_lo = (_Float16*)smem + 16384;

    const int tid    = threadIdx.x;
    const int wid    = tid >> 6;
    const int lane   = tid & 63;
    const int wave_m = wid >> 1;    // 0..1 : 64-row half
    const int wave_n = wid & 1;     // 0..1 : 128-col half
    const int lane15 = lane & 15;
    const int quad   = lane >> 4;

    // default mapping: all concurrent blocks share one slice's B-panel
    const int ns   = blockIdx.y;
    const int row0 = blockIdx.x * BMT;
    const int c00  = ns * SLICE_CODES;

    // per-thread swizzled frag offsets (half-index within a plane)
    int aoff[4], boff[8];
#pragma unroll
    for (int i = 0; i < 4; ++i)
        aoff[i] = sw32(wave_m * 64 + i * 16 + lane15, quad);
#pragma unroll
    for (int i = 0; i < 8; ++i)
        boff[i] = sw32(wave_n * 128 + i * 16 + lane15, quad);

    // staging coords
    const int r4 = lane >> 2;      // row-in-16 for async wave-loads
    const int sl = lane & 3;       // 16B slot
    const int s_r0 = tid >> 3;     // fallback A staging coords (0..31)
    const int s_cg = tid & 7;      // 4-float group (0..7)

    // stage one (nt, kc) step: B 16 wave-loads/plane-pair, A 8
    auto stage = [&](int nt, int kc) {
        const int c0 = c00 + nt * BNT;
#pragma unroll
        for (int i = 0; i < 4; ++i) {
            const int L   = wid * 4 + i;          // 0..15
            const int row = L * 16 + r4;
            const int g   = sl ^ ((row >> 1) & 3);    // inverse swizzle
            const size_t kb = (size_t)(c0 + row) * DIM + kc * BK + g * 8;
            async_copy16(Bs_hi + L * 512, cb_hi + kb);
            async_copy16(Bs_lo + L * 512, cb_lo + kb);
        }
        if constexpr (PRESPLIT) {
#pragma unroll
            for (int i = 0; i < 2; ++i) {
                const int L   = wid * 2 + i;      // 0..7
                const int row = L * 16 + r4;
                const int g   = sl ^ ((row >> 1) & 3);
                const size_t ka = (size_t)(row0 + row) * DIM + kc * BK + g * 8;
                async_copy16(As_hi + L * 512, ze_hi + ka);
                async_copy16(As_lo + L * 512, ze_lo + ka);
            }
        } else {
            // fallback: stage A hi+lo from one fp32 read, swizzled ds_write
#pragma unroll
            for (int rr = 0; rr < 4; ++rr) {
                const int row = rr * 32 + s_r0;
                float4 v = *(const float4*)&z_e[(size_t)(row0 + row) * DIM + kc * BK + s_cg * 4];
                f16x4 hi = {(_Float16)v.x, (_Float16)v.y, (_Float16)v.z, (_Float16)v.w};
                f16x4 lo = {(_Float16)(v.x - (float)hi[0]), (_Float16)(v.y - (float)hi[1]),
                            (_Float16)(v.z - (float)hi[2]), (_Float16)(v.w - (float)hi[3])};
                const int a = sw32(row, s_cg >> 1) + ((s_cg & 1) << 2);
                *(f16x4*)&As_hi[a] = hi;
                *(f16x4*)&As_lo[a] = lo;
            }
        }
    };

    float minv[4][4];
    int   mini[4][4];
#pragma unroll
    for (int mi = 0; mi < 4; ++mi)
#pragma unroll
        for (int r = 0; r < 4; ++r) { minv[mi][r] = __builtin_inff(); mini[mi][r] = 0; }

#pragma unroll 1
    for (int nt = 0; nt < NTILES; ++nt) {
        const int c0 = c00 + nt * BNT;
        f32x4 acc[4][8];
#pragma unroll
        for (int mi = 0; mi < 4; ++mi)
#pragma unroll
            for (int ni = 0; ni < 8; ++ni) acc[mi][ni] = (f32x4){0.f, 0.f, 0.f, 0.f};

#pragma unroll 1
        for (int kc = 0; kc < CHUNKS; ++kc) {
            __syncthreads();   // previous step's readers done; LDS free
            stage(nt, kc);
            __syncthreads();   // single async-drain point

            // A frags for this 32-k step (8 reads)
            f16x8 ah[4], al[4];
#pragma unroll
            for (int mi = 0; mi < 4; ++mi) {
                ah[mi] = *(const f16x8*)&As_hi[aoff[mi]];
                al[mi] = *(const f16x8*)&As_lo[aoff[mi]];
            }
            // two ni-halves: bounds B-frag live range (register pressure)
#pragma unroll
            for (int nh = 0; nh < 2; ++nh) {
                f16x8 bh[4], bl[4];
#pragma unroll
                for (int nj = 0; nj < 4; ++nj) {
                    bh[nj] = *(const f16x8*)&Bs_hi[boff[nh * 4 + nj]];
                    bl[nj] = *(const f16x8*)&Bs_lo[boff[nh * 4 + nj]];
                }
                // pass 1: Ahi x Bhi
#pragma unroll
                for (int mi = 0; mi < 4; ++mi)
#pragma unroll
                    for (int nj = 0; nj < 4; ++nj)
                        acc[mi][nh * 4 + nj] = __builtin_amdgcn_mfma_f32_16x16x32_f16(
                            ah[mi], bh[nj], acc[mi][nh * 4 + nj], 0, 0, 0);
                // pass 2: Alo x Bhi
#pragma unroll
                for (int mi = 0; mi < 4; ++mi)
#pragma unroll
                    for (int nj = 0; nj < 4; ++nj)
                        acc[mi][nh * 4 + nj] = __builtin_amdgcn_mfma_f32_16x16x32_f16(
                            al[mi], bh[nj], acc[mi][nh * 4 + nj], 0, 0, 0);
                // pass 3: Ahi x Blo
#pragma unroll
                for (int mi = 0; mi < 4; ++mi)
#pragma unroll
                    for (int nj = 0; nj < 4; ++nj)
                        acc[mi][nh * 4 + nj] = __builtin_amdgcn_mfma_f32_16x16x32_f16(
                            ah[mi], bl[nj], acc[mi][nh * 4 + nj], 0, 0, 0);
            }
        }

        // --- score = ||c||^2 - 2*dot; running argmin ---
#pragma unroll
        for (int ni = 0; ni < 8; ++ni) {
            const int c = c0 + wave_n * 128 + ni * 16 + lane15;
            const float nrm = nc[c];
#pragma unroll
            for (int mi = 0; mi < 4; ++mi)
#pragma unroll
                for (int r = 0; r < 4; ++r) {
                    const float v = fmaf(-2.0f, acc[mi][ni][r], nrm);
                    if (v < minv[mi][r]) { minv[mi][r] = v; mini[mi][r] = c; }
                }
        }
    }

    // --- block argmin reduction; write per-slice partial ---
    __syncthreads();
    float* redv = (float*)smem;            // [2 wave_n][128 rows][16 lanes]
    int*   redi = (int*)(smem + 16384);
#pragma unroll
    for (int mi = 0; mi < 4; ++mi)
#pragma unroll
        for (int r = 0; r < 4; ++r) {
            const int rl = wave_m * 64 + mi * 16 + quad * 4 + r;
            const int o = wave_n * 2048 + rl * 16 + lane15;
            redv[o] = minv[mi][r];
            redi[o] = mini[mi][r];
        }
    __syncthreads();
    if (tid < BMT) {
        float bv = __builtin_inff();
        int   bi = 0x7fffffff;
        for (int j = 0; j < 32; ++j) {
            const int o = (j >= 16 ? 2048 : 0) + tid * 16 + (j & 15);
            const float v = redv[o];
            const int   i = redi[o];
            if (v < bv || (v == bv && i < bi)) { bv = v; bi = i; }
        }
        partials[(size_t)(row0 + tid) * SLICES + ns] = make_float2(bv, __int_as_float(bi));
    }
}

// ---------------------------------------------------------------------------
// Kernel 3: merge slice partials -> final idx; gather z_q; loss partial.
__global__ void vq_merge_kernel(const float* __restrict__ z_e,
                                const float* __restrict__ cb,
                                const float2* __restrict__ partials,
                                float* __restrict__ out,
                                float* __restrict__ accum) {
    __shared__ float wpart[4];
    const int wid  = threadIdx.x >> 6;
    const int lane = threadIdx.x & 63;
    const int tbase = blockIdx.x * 64 + wid * 16;
    float part = 0.0f;
#pragma unroll 1
    for (int t = 0; t < 16; ++t) {
        const int token = tbase + t;
        float bv = __builtin_inff();
        int   bi = 0;
        // slices hold ascending disjoint code ranges; strict < => lowest index on tie
#pragma unroll
        for (int s = 0; s < SLICES; ++s) {
            float2 p = partials[(size_t)token * SLICES + s];  // wave-uniform -> broadcast
            if (p.x < bv) { bv = p.x; bi = __float_as_int(p.y); }
        }
        const int code = bi & (N_CODES - 1);
        const float4* zp = (const float4*)(z_e + (size_t)token * DIM);
        const float4* cp = (const float4*)(cb + (size_t)code * DIM);
        float4* op = (float4*)out + (size_t)token * (DIM / 4);
#pragma unroll
        for (int i = 0; i < 2; ++i) {
            const int e = lane + i * 64;
            float4 z = zp[e];
            float4 q = cp[e];
            op[e] = q;   // z_q_st value == z_q (exact fp32 codebook row)
            float dx = z.x - q.x, dy = z.y - q.y, dz = z.z - q.z, dw = z.w - q.w;
            part += dx * dx + dy * dy + dz * dz + dw * dw;
        }
        if (lane == 0) out[OUT_IDX + token] = (float)code;
    }
#pragma unroll
    for (int off = 32; off > 0; off >>= 1) part += __shfl_down(part, off);
    if (lane == 0) wpart[wid] = part;
    __syncthreads();
    if (threadIdx.x == 0) atomicAdd(accum, wpart[0] + wpart[1] + wpart[2] + wpart[3]);
}

// ---------------------------------------------------------------------------
// Kernel 4: finalize losses
__global__ void vq_finalize_kernel(const float* __restrict__ accum,
                                   float* __restrict__ out) {
    const float c = *accum * (1.0f / (float)(N_TOKENS * DIM));
    out[OUT_VQ]     = 0.25f * c;
    out[OUT_COMMIT] = c;
}

// ---------------------------------------------------------------------------
extern "C" void kernel_launch(void* const* d_in, const int* in_sizes, int n_in,
                              void* d_out, int out_size, void* d_ws, size_t ws_size,
                              hipStream_t stream) {
    const float* z_e = (const float*)d_in[0];
    const float* cb  = (const float*)d_in[1];
    float* out = (float*)d_out;

    _Float16* cb_hi = (_Float16*)((char*)d_ws + WS_CBHI);
    _Float16* cb_lo = (_Float16*)((char*)d_ws + WS_CBLO);
    float*    nc    = (float*)((char*)d_ws + WS_NC);
    float2*   part  = (float2*)((char*)d_ws + WS_PART);
    float*    accum = (float*)((char*)d_ws + WS_ACC);
    _Float16* ze_hi = (_Float16*)((char*)d_ws + WS_ZEHI);
    _Float16* ze_lo = (_Float16*)((char*)d_ws + WS_ZELO);

    const bool fast = (ws_size >= (size_t)WS_NEED_FAST);  // call-invariant -> graph-safe

    hipLaunchKernelGGL(vq_prep_cb_kernel, dim3(N_CODES / 4), dim3(256), 0, stream,
                       cb, cb_hi, cb_lo, nc, accum);
    if (fast) {
        hipLaunchKernelGGL(vq_prep_ze_kernel, dim3(N_TOKENS / 4), dim3(256), 0, stream,
                           z_e, ze_hi, ze_lo);
        hipLaunchKernelGGL((vq_main_kernel<true>), dim3(N_TOKENS / BMT, SLICES), dim3(256), 0, stream,
                           z_e, ze_hi, ze_lo, cb_hi, cb_lo, nc, part);
    } else {
        hipLaunchKernelGGL((vq_main_kernel<false>), dim3(N_TOKENS / BMT, SLICES), dim3(256), 0, stream,
                           z_e, ze_hi, ze_lo, cb_hi, cb_lo, nc, part);
    }
    hipLaunchKernelGGL(vq_merge_kernel, dim3(N_TOKENS / 64), dim3(256), 0, stream,
                       z_e, cb, part, out, accum);
    hipLaunchKernelGGL(vq_finalize_kernel, dim3(1), dim3(1), 0, stream, accum, out);
}

// Round 6
// 836.061 us; speedup vs baseline: 1.1267x; 1.1267x over previous
//
#include <hip/hip_runtime.h>

// Problem constants (fixed by the reference)
#define N_TOKENS 32768
#define N_CODES  8192
#define DIM      512

// Tiling: 128 token-rows x 256 codes per tile, BK=32, 4 code-slices.
// Round-5 post-mortem: the 64x128 wave tile cut LDS reads/FLOP and staging
// by the predicted 25% (FETCH_SIZE -27%), but register pressure (acc 128 +
// 64 live B-frag VGPRs) spilled to scratch: WRITE_SIZE 4MB -> 117MB, -10%.
// This round: same tiling, B-frags live range cut 8 pairs -> 1 pair.
#define BMT 128
#define BNT 256
#define SLICES 4
#define SLICE_CODES (N_CODES / SLICES)   // 2048
#define NTILES (SLICE_CODES / BNT)       // 8
#define BK 32
#define CHUNKS (DIM / BK)                // 16

// Output layout (FP32 elements, reference return order)
#define OUT_VQ     16777216
#define OUT_COMMIT 16777217
#define OUT_IDX    16777218

// Workspace byte offsets
#define WS_CBHI 0                         //  8 MB codebook f16 hi
#define WS_CBLO 8388608                   //  8 MB codebook f16 lo
#define WS_NC   16777216                  // 32 KB code norms
#define WS_PART 16809984                  //  1 MB slice partials
#define WS_ACC  17858560                  //  4 B loss accum
#define WS_ZEHI 18874368                  // 32 MB z_e f16 hi
#define WS_ZELO 52428800                  // 32 MB z_e f16 lo
#define WS_NEED_FAST 85983232             // total for pre-split-A path

typedef _Float16 f16x8 __attribute__((ext_vector_type(8)));
typedef _Float16 f16x4 __attribute__((ext_vector_type(4)));
typedef float    f32x4 __attribute__((ext_vector_type(4)));

// Swizzled LDS half-index for (row, kgrp) in a [rows][32]-half plane (row
// stride 64B). slot = kgrp ^ ((row>>1)&3); with row parity this gives the
// free 2-lanes-per-bank minimum for wave64 b128 reads.
__device__ __forceinline__ int sw32(int row, int kgrp) {
    return row * 32 + (((kgrp ^ ((row >> 1) & 3))) << 3);
}

// async 16B global->LDS (lds dest = wave-uniform base + lane*16)
__device__ __forceinline__ void async_copy16(void* lds, const void* g) {
    __builtin_amdgcn_global_load_lds(
        (const __attribute__((address_space(1))) unsigned int*)g,
        (__attribute__((address_space(3))) unsigned int*)lds,
        16, 0, 0);
}

// ---------------------------------------------------------------------------
// Kernel 1a: codebook -> planar f16 hi/lo + squared norms + zero accum.
__global__ void vq_prep_cb_kernel(const float* __restrict__ cb,
                                  _Float16* __restrict__ cb_hi,
                                  _Float16* __restrict__ cb_lo,
                                  float* __restrict__ nc,
                                  float* __restrict__ accum) {
    if (blockIdx.x == 0 && threadIdx.x == 0) *accum = 0.0f;
    const int wid  = threadIdx.x >> 6;
    const int lane = threadIdx.x & 63;
    const int row  = blockIdx.x * 4 + wid;
    const float4* src = (const float4*)(cb + (size_t)row * DIM);
    float4 v0 = src[lane * 2];
    float4 v1 = src[lane * 2 + 1];
    float s = v0.x*v0.x + v0.y*v0.y + v0.z*v0.z + v0.w*v0.w
            + v1.x*v1.x + v1.y*v1.y + v1.z*v1.z + v1.w*v1.w;
    f16x8 hi = {(_Float16)v0.x, (_Float16)v0.y, (_Float16)v0.z, (_Float16)v0.w,
                (_Float16)v1.x, (_Float16)v1.y, (_Float16)v1.z, (_Float16)v1.w};
    f16x8 lo = {(_Float16)(v0.x - (float)hi[0]), (_Float16)(v0.y - (float)hi[1]),
                (_Float16)(v0.z - (float)hi[2]), (_Float16)(v0.w - (float)hi[3]),
                (_Float16)(v1.x - (float)hi[4]), (_Float16)(v1.y - (float)hi[5]),
                (_Float16)(v1.z - (float)hi[6]), (_Float16)(v1.w - (float)hi[7])};
    *(f16x8*)&cb_hi[(size_t)row * DIM + lane * 8] = hi;
    *(f16x8*)&cb_lo[(size_t)row * DIM + lane * 8] = lo;
#pragma unroll
    for (int off = 32; off > 0; off >>= 1) s += __shfl_down(s, off);
    if (lane == 0) nc[row] = s;
}

// Kernel 1b: z_e -> planar f16 hi/lo (fast path only).
__global__ void vq_prep_ze_kernel(const float* __restrict__ z_e,
                                  _Float16* __restrict__ ze_hi,
                                  _Float16* __restrict__ ze_lo) {
    const int wid  = threadIdx.x >> 6;
    const int lane = threadIdx.x & 63;
    const int row  = blockIdx.x * 4 + wid;
    const float4* src = (const float4*)(z_e + (size_t)row * DIM);
    float4 v0 = src[lane * 2];
    float4 v1 = src[lane * 2 + 1];
    f16x8 hi = {(_Float16)v0.x, (_Float16)v0.y, (_Float16)v0.z, (_Float16)v0.w,
                (_Float16)v1.x, (_Float16)v1.y, (_Float16)v1.z, (_Float16)v1.w};
    f16x8 lo = {(_Float16)(v0.x - (float)hi[0]), (_Float16)(v0.y - (float)hi[1]),
                (_Float16)(v0.z - (float)hi[2]), (_Float16)(v0.w - (float)hi[3]),
                (_Float16)(v1.x - (float)hi[4]), (_Float16)(v1.y - (float)hi[5]),
                (_Float16)(v1.z - (float)hi[6]), (_Float16)(v1.w - (float)hi[7])};
    *(f16x8*)&ze_hi[(size_t)row * DIM + lane * 8] = hi;
    *(f16x8*)&ze_lo[(size_t)row * DIM + lane * 8] = lo;
}

// ---------------------------------------------------------------------------
// Kernel 2: 3-plane f16-split GEMM + per-slice argmin.
// Round-0 sync structure (stage -> drain-barrier -> compute -> barrier).
// Wave tile 64x128 (2x2 waves over 128x256): 24 ds_read_b128 per wave per
// 32-k step (-25% LDS reads/FLOP vs 64x64 — the measured binding pipe).
// Register diet vs round 5: B-frags read one nj at a time (live pair = 8
// VGPRs, was 64); boff recomputed inline. Target: zero scratch.
template <bool PRESPLIT>
__global__ __launch_bounds__(256, 2)
void vq_main_kernel(const float* __restrict__ z_e,
                    const _Float16* __restrict__ ze_hi,
                    const _Float16* __restrict__ ze_lo,
                    const _Float16* __restrict__ cb_hi,
                    const _Float16* __restrict__ cb_lo,
                    const float* __restrict__ nc,
                    float2* __restrict__ partials) {
    // 48 KB LDS (half-indices): As_hi 0, As_lo 4096, Bs_hi 8192, Bs_lo 16384
    //   A planes: [128][32] halves (8KB each); B planes: [256][32] (16KB each)
    __shared__ __align__(16) unsigned char smem[49152];
    _Float16* As_hi = (_Float16*)smem;
    _Float16* As_lo = (_Float16*)smem + 4096;
    _Float16* Bs_hi = (_Float16*)smem + 8192;
    _Float16* Bs_lo = (_Float16*)smem + 16384;

    const int tid    = threadIdx.x;
    const int wid    = tid >> 6;
    const int lane   = tid & 63;
    const int wave_m = wid >> 1;    // 0..1 : 64-row half
    const int wave_n = wid & 1;     // 0..1 : 128-col half
    const int lane15 = lane & 15;
    const int quad   = lane >> 4;

    // default mapping: all concurrent blocks share one slice's B-panel
    const int ns   = blockIdx.y;
    const int row0 = blockIdx.x * BMT;
    const int c00  = ns * SLICE_CODES;

    // A frag offsets (all 4 live anyway); B offsets recomputed inline
    int aoff[4];
#pragma unroll
    for (int i = 0; i < 4; ++i)
        aoff[i] = sw32(wave_m * 64 + i * 16 + lane15, quad);

    // staging coords
    const int r4 = lane >> 2;      // row-in-16 for async wave-loads
    const int sl = lane & 3;       // 16B slot
    const int s_r0 = tid >> 3;     // fallback A staging coords (0..31)
    const int s_cg = tid & 7;      // 4-float group (0..7)

    // stage one (nt, kc) step: B 16 wave-loads/plane-pair, A 8
    auto stage = [&](int nt, int kc) {
        const int c0 = c00 + nt * BNT;
#pragma unroll
        for (int i = 0; i < 4; ++i) {
            const int L   = wid * 4 + i;          // 0..15
            const int row = L * 16 + r4;
            const int g   = sl ^ ((row >> 1) & 3);    // inverse swizzle
            const size_t kb = (size_t)(c0 + row) * DIM + kc * BK + g * 8;
            async_copy16(Bs_hi + L * 512, cb_hi + kb);
            async_copy16(Bs_lo + L * 512, cb_lo + kb);
        }
        if constexpr (PRESPLIT) {
#pragma unroll
            for (int i = 0; i < 2; ++i) {
                const int L   = wid * 2 + i;      // 0..7
                const int row = L * 16 + r4;
                const int g   = sl ^ ((row >> 1) & 3);
                const size_t ka = (size_t)(row0 + row) * DIM + kc * BK + g * 8;
                async_copy16(As_hi + L * 512, ze_hi + ka);
                async_copy16(As_lo + L * 512, ze_lo + ka);
            }
        } else {
            // fallback: stage A hi+lo from one fp32 read, swizzled ds_write
#pragma unroll
            for (int rr = 0; rr < 4; ++rr) {
                const int row = rr * 32 + s_r0;
                float4 v = *(const float4*)&z_e[(size_t)(row0 + row) * DIM + kc * BK + s_cg * 4];
                f16x4 hi = {(_Float16)v.x, (_Float16)v.y, (_Float16)v.z, (_Float16)v.w};
                f16x4 lo = {(_Float16)(v.x - (float)hi[0]), (_Float16)(v.y - (float)hi[1]),
                            (_Float16)(v.z - (float)hi[2]), (_Float16)(v.w - (float)hi[3])};
                const int a = sw32(row, s_cg >> 1) + ((s_cg & 1) << 2);
                *(f16x4*)&As_hi[a] = hi;
                *(f16x4*)&As_lo[a] = lo;
            }
        }
    };

    float minv[4][4];
    int   mini[4][4];
#pragma unroll
    for (int mi = 0; mi < 4; ++mi)
#pragma unroll
        for (int r = 0; r < 4; ++r) { minv[mi][r] = __builtin_inff(); mini[mi][r] = 0; }

#pragma unroll 1
    for (int nt = 0; nt < NTILES; ++nt) {
        const int c0 = c00 + nt * BNT;
        f32x4 acc[4][8];
#pragma unroll
        for (int mi = 0; mi < 4; ++mi)
#pragma unroll
            for (int ni = 0; ni < 8; ++ni) acc[mi][ni] = (f32x4){0.f, 0.f, 0.f, 0.f};

#pragma unroll 1
        for (int kc = 0; kc < CHUNKS; ++kc) {
            __syncthreads();   // previous step's readers done; LDS free
            stage(nt, kc);
            __syncthreads();   // single async-drain point

            // A frags for this 32-k step (8 reads, all live)
            f16x8 ah[4], al[4];
#pragma unroll
            for (int mi = 0; mi < 4; ++mi) {
                ah[mi] = *(const f16x8*)&As_hi[aoff[mi]];
                al[mi] = *(const f16x8*)&As_lo[aoff[mi]];
            }
            // B frags one nj at a time: live pair = 8 VGPRs (round-5 spill fix)
#pragma unroll
            for (int nj = 0; nj < 8; ++nj) {
                const int b = sw32(wave_n * 128 + nj * 16 + lane15, quad);
                const f16x8 bh = *(const f16x8*)&Bs_hi[b];
                const f16x8 bl = *(const f16x8*)&Bs_lo[b];
                // pass 1: Ahi x Bhi  (acc reuse distance 4)
#pragma unroll
                for (int mi = 0; mi < 4; ++mi)
                    acc[mi][nj] = __builtin_amdgcn_mfma_f32_16x16x32_f16(
                        ah[mi], bh, acc[mi][nj], 0, 0, 0);
                // pass 2: Alo x Bhi
#pragma unroll
                for (int mi = 0; mi < 4; ++mi)
                    acc[mi][nj] = __builtin_amdgcn_mfma_f32_16x16x32_f16(
                        al[mi], bh, acc[mi][nj], 0, 0, 0);
                // pass 3: Ahi x Blo
#pragma unroll
                for (int mi = 0; mi < 4; ++mi)
                    acc[mi][nj] = __builtin_amdgcn_mfma_f32_16x16x32_f16(
                        ah[mi], bl, acc[mi][nj], 0, 0, 0);
            }
        }

        // --- score = ||c||^2 - 2*dot; running argmin ---
#pragma unroll
        for (int ni = 0; ni < 8; ++ni) {
            const int c = c0 + wave_n * 128 + ni * 16 + lane15;
            const float nrm = nc[c];
#pragma unroll
            for (int mi = 0; mi < 4; ++mi)
#pragma unroll
                for (int r = 0; r < 4; ++r) {
                    const float v = fmaf(-2.0f, acc[mi][ni][r], nrm);
                    if (v < minv[mi][r]) { minv[mi][r] = v; mini[mi][r] = c; }
                }
        }
    }

    // --- block argmin reduction; write per-slice partial ---
    __syncthreads();
    float* redv = (float*)smem;            // [2 wave_n][128 rows][16 lanes]
    int*   redi = (int*)(smem + 16384);
#pragma unroll
    for (int mi = 0; mi < 4; ++mi)
#pragma unroll
        for (int r = 0; r < 4; ++r) {
            const int rl = wave_m * 64 + mi * 16 + quad * 4 + r;
            const int o = wave_n * 2048 + rl * 16 + lane15;
            redv[o] = minv[mi][r];
            redi[o] = mini[mi][r];
        }
    __syncthreads();
    if (tid < BMT) {
        float bv = __builtin_inff();
        int   bi = 0x7fffffff;
        for (int j = 0; j < 32; ++j) {
            const int o = (j >= 16 ? 2048 : 0) + tid * 16 + (j & 15);
            const float v = redv[o];
            const int   i = redi[o];
            if (v < bv || (v == bv && i < bi)) { bv = v; bi = i; }
        }
        partials[(size_t)(row0 + tid) * SLICES + ns] = make_float2(bv, __int_as_float(bi));
    }
}

// ---------------------------------------------------------------------------
// Kernel 3: merge slice partials -> final idx; gather z_q; loss partial.
__global__ void vq_merge_kernel(const float* __restrict__ z_e,
                                const float* __restrict__ cb,
                                const float2* __restrict__ partials,
                                float* __restrict__ out,
                                float* __restrict__ accum) {
    __shared__ float wpart[4];
    const int wid  = threadIdx.x >> 6;
    const int lane = threadIdx.x & 63;
    const int tbase = blockIdx.x * 64 + wid * 16;
    float part = 0.0f;
#pragma unroll 1
    for (int t = 0; t < 16; ++t) {
        const int token = tbase + t;
        float bv = __builtin_inff();
        int   bi = 0;
        // slices hold ascending disjoint code ranges; strict < => lowest index on tie
#pragma unroll
        for (int s = 0; s < SLICES; ++s) {
            float2 p = partials[(size_t)token * SLICES + s];  // wave-uniform -> broadcast
            if (p.x < bv) { bv = p.x; bi = __float_as_int(p.y); }
        }
        const int code = bi & (N_CODES - 1);
        const float4* zp = (const float4*)(z_e + (size_t)token * DIM);
        const float4* cp = (const float4*)(cb + (size_t)code * DIM);
        float4* op = (float4*)out + (size_t)token * (DIM / 4);
#pragma unroll
        for (int i = 0; i < 2; ++i) {
            const int e = lane + i * 64;
            float4 z = zp[e];
            float4 q = cp[e];
            op[e] = q;   // z_q_st value == z_q (exact fp32 codebook row)
            float dx = z.x - q.x, dy = z.y - q.y, dz = z.z - q.z, dw = z.w - q.w;
            part += dx * dx + dy * dy + dz * dz + dw * dw;
        }
        if (lane == 0) out[OUT_IDX + token] = (float)code;
    }
#pragma unroll
    for (int off = 32; off > 0; off >>= 1) part += __shfl_down(part, off);
    if (lane == 0) wpart[wid] = part;
    __syncthreads();
    if (threadIdx.x == 0) atomicAdd(accum, wpart[0] + wpart[1] + wpart[2] + wpart[3]);
}

// ---------------------------------------------------------------------------
// Kernel 4: finalize losses
__global__ void vq_finalize_kernel(const float* __restrict__ accum,
                                   float* __restrict__ out) {
    const float c = *accum * (1.0f / (float)(N_TOKENS * DIM));
    out[OUT_VQ]     = 0.25f * c;
    out[OUT_COMMIT] = c;
}

// ---------------------------------------------------------------------------
extern "C" void kernel_launch(void* const* d_in, const int* in_sizes, int n_in,
                              void* d_out, int out_size, void* d_ws, size_t ws_size,
                              hipStream_t stream) {
    const float* z_e = (const float*)d_in[0];
    const float* cb  = (const float*)d_in[1];
    float* out = (float*)d_out;

    _Float16* cb_hi = (_Float16*)((char*)d_ws + WS_CBHI);
    _Float16* cb_lo = (_Float16*)((char*)d_ws + WS_CBLO);
    float*    nc    = (float*)((char*)d_ws + WS_NC);
    float2*   part  = (float2*)((char*)d_ws + WS_PART);
    float*    accum = (float*)((char*)d_ws + WS_ACC);
    _Float16* ze_hi = (_Float16*)((char*)d_ws + WS_ZEHI);
    _Float16* ze_lo = (_Float16*)((char*)d_ws + WS_ZELO);

    const bool fast = (ws_size >= (size_t)WS_NEED_FAST);  // call-invariant -> graph-safe

    hipLaunchKernelGGL(vq_prep_cb_kernel, dim3(N_CODES / 4), dim3(256), 0, stream,
                       cb, cb_hi, cb_lo, nc, accum);
    if (fast) {
        hipLaunchKernelGGL(vq_prep_ze_kernel, dim3(N_TOKENS / 4), dim3(256), 0, stream,
                           z_e, ze_hi, ze_lo);
        hipLaunchKernelGGL((vq_main_kernel<true>), dim3(N_TOKENS / BMT, SLICES), dim3(256), 0, stream,
                           z_e, ze_hi, ze_lo, cb_hi, cb_lo, nc, part);
    } else {
        hipLaunchKernelGGL((vq_main_kernel<false>), dim3(N_TOKENS / BMT, SLICES), dim3(256), 0, stream,
                           z_e, ze_hi, ze_lo, cb_hi, cb_lo, nc, part);
    }
    hipLaunchKernelGGL(vq_merge_kernel, dim3(N_TOKENS / 64), dim3(256), 0, stream,
                       z_e, cb, part, out, accum);
    hipLaunchKernelGGL(vq_finalize_kernel, dim3(1), dim3(1), 0, stream, accum, out);
}